// Round 3
// baseline (1234.072 us; speedup 1.0000x reference)
//
#include <hip/hip_runtime.h>
#include <stdint.h>

#define NN    4096
#define BATCH 8
#define IC    256
#define HC    512
#define OC    256
#define MTOT  (BATCH * NN)

typedef float    f32x4  __attribute__((ext_vector_type(4)));
typedef __bf16   bf16x8 __attribute__((ext_vector_type(8)));
typedef uint16_t u16x8  __attribute__((ext_vector_type(8)));
typedef uint16_t u16x4  __attribute__((ext_vector_type(4)));

__device__ __forceinline__ uint16_t f2b(float f) {
  union { float f; uint32_t u; } v; v.f = f;
  return (uint16_t)((v.u + 0x7FFFu + ((v.u >> 16) & 1u)) >> 16);
}

__device__ __forceinline__ void gl_lds16(const void* g, void* l) {
  __builtin_amdgcn_global_load_lds(
      (const __attribute__((address_space(1))) uint32_t*)g,
      (__attribute__((address_space(3))) uint32_t*)l, 16, 0, 0);
}

// ---------- pass1: rowsum->dinv  +  Abf = bf16(A + I), tiled+swizzled ----------
// Abf layout: [strip = b*32+mt][kt 128][row 128][slot 4][8]; slot s holds
// k-group g = s ^ (row&3). Tile (strip,kt) = 8 KB contiguous.
__global__ __launch_bounds__(512) void prep_kernel(const float* __restrict__ A,
                                                   uint16_t* __restrict__ Abf,
                                                   float* __restrict__ dinv) {
  const int bid = blockIdx.x;                 // 256 = 8 b * 32 mt
  const int b = bid & 7, mt = bid >> 3;
  const int t = threadIdx.x;
  const int r = t >> 2, g = t & 3;            // row 0..127, k-group 0..3
  const int rowl = mt * 128 + r;              // row within batch
  const float* Ap = A + ((size_t)b * NN + rowl) * NN + g * 8;
  uint16_t* Op = Abf + ((size_t)(b * 32 + mt) << 19) + r * 32 + ((g ^ (r & 3)) << 3);
  float s = 0.f;
  for (int kt = 0; kt < 128; ++kt) {
    f32x4 a0 = *(const f32x4*)(Ap + kt * 32);
    f32x4 a1 = *(const f32x4*)(Ap + kt * 32 + 4);
    int dj = rowl - (kt * 32 + g * 8);        // diag element position, if any
    u16x8 o;
#pragma unroll
    for (int e = 0; e < 4; ++e) {
      float v0 = a0[e], v1 = a1[e];
      s += v0 + v1;
      if (dj == e)     v0 += 1.f;
      if (dj == e + 4) v1 += 1.f;
      o[e] = f2b(v0); o[e + 4] = f2b(v1);
    }
    *(u16x8*)(Op + (size_t)kt * 4096) = o;
  }
  __shared__ float red[512];
  red[t] = s;
  __syncthreads();
  if (t < 128) {
    float deg = red[t * 4] + red[t * 4 + 1] + red[t * 4 + 2] + red[t * 4 + 3] + 1.0f;
    dinv[b * NN + mt * 128 + t] = 1.0f / sqrtf(deg);
  }
}

// ---------- xw: Vt = (dinv .* (X @ W))^T, swizzled kt32 tiles ----------
// Vt layout: [b][kt 128][n NC][slot 4][8], slot s holds k-group s^(n&3)
template<bool ABF16, int KTOT, int NC>
__global__ __launch_bounds__(256, 2) void xw_kernel(const void* __restrict__ Av,
                                                    const float* __restrict__ W,
                                                    const float* __restrict__ dinv,
                                                    uint16_t* __restrict__ Vt) {
  constexpr int LDT = 72;
  __shared__ uint16_t smem[18432];
  uint16_t* as_ = smem;
  uint16_t* wt_ = smem + 9216;
  const int t = threadIdx.x;
  const int m0 = blockIdx.x * 128;
  const int n0 = blockIdx.y * 128;
  const int lane = t & 63, wid = t >> 6;
  const int wm = wid >> 1, wn = wid & 1;
  f32x4 acc[4][4] = {};

  for (int kt = 0; kt < KTOT / 64; ++kt) {
    const int k0 = kt * 64;
    __syncthreads();
    if constexpr (!ABF16) {
      const float* Ap = (const float*)Av;
      const int c4 = t & 15, r0 = t >> 4;
#pragma unroll
      for (int i = 0; i < 8; ++i) {
        int r = r0 + 16 * i;
        f32x4 v = *(const f32x4*)(Ap + (size_t)(m0 + r) * KTOT + k0 + c4 * 4);
        uint32_t lo = f2b(v[0]) | ((uint32_t)f2b(v[1]) << 16);
        uint32_t hi = f2b(v[2]) | ((uint32_t)f2b(v[3]) << 16);
        *(uint2*)&as_[r * LDT + c4 * 4] = make_uint2(lo, hi);
      }
    } else {
      const uint16_t* Ap = (const uint16_t*)Av;
      const int c8 = t & 7, r0 = t >> 3;
#pragma unroll
      for (int i = 0; i < 4; ++i) {
        int r = r0 + 32 * i;
        u16x8 v = *(const u16x8*)(Ap + (size_t)(m0 + r) * KTOT + k0 + c8 * 8);
        *(u16x8*)&as_[r * LDT + c8 * 8] = v;
      }
    }
    {
      const int n4 = t & 31, kq = t >> 5;
#pragma unroll
      for (int i = 0; i < 8; ++i) {
        int k = kq + 8 * i;
        f32x4 v = *(const f32x4*)(W + (size_t)(k0 + k) * NC + n0 + n4 * 4);
        uint16_t hv[4] = { f2b(v[0]), f2b(v[1]), f2b(v[2]), f2b(v[3]) };
#pragma unroll
        for (int w = 0; w < 4; ++w) {
          int we = (w + n4) & 3;
          wt_[(n4 * 4 + we) * LDT + k] = hv[we];
        }
      }
    }
    __syncthreads();
#pragma unroll
    for (int kk = 0; kk < 2; ++kk) {
      bf16x8 bfr[4], afr[4];
#pragma unroll
      for (int fn = 0; fn < 4; ++fn)
        bfr[fn] = *(const bf16x8*)&wt_[(wn * 64 + fn * 16 + (lane & 15)) * LDT + kk * 32 + (lane >> 4) * 8];
#pragma unroll
      for (int fm = 0; fm < 4; ++fm)
        afr[fm] = *(const bf16x8*)&as_[(wm * 64 + fm * 16 + (lane & 15)) * LDT + kk * 32 + (lane >> 4) * 8];
#pragma unroll
      for (int fm = 0; fm < 4; ++fm)
#pragma unroll
        for (int fn = 0; fn < 4; ++fn)
          acc[fm][fn] = __builtin_amdgcn_mfma_f32_16x16x32_bf16(afr[fm], bfr[fn], acc[fm][fn], 0, 0, 0);
    }
  }
  // transpose epilogue via LDS bounce; scale by dinv[row]; write swizzled Vt
  const int b = m0 >> 12;
  const int klocal = m0 & 4095;
  __syncthreads();
  uint16_t* lv = smem;                        // [128 n][144]
#pragma unroll
  for (int fm = 0; fm < 4; ++fm)
#pragma unroll
    for (int fn = 0; fn < 4; ++fn) {
      int nloc = wn * 64 + fn * 16 + (lane & 15);
      int ml0  = wm * 64 + fm * 16 + (lane >> 4) * 4;
      u16x4 pk;
#pragma unroll
      for (int r = 0; r < 4; ++r)
        pk[r] = f2b(acc[fm][fn][r] * dinv[m0 + ml0 + r]);
      *(u16x4*)&lv[nloc * 144 + ml0] = pk;
    }
  __syncthreads();
#pragma unroll
  for (int i = 0; i < 8; ++i) {
    int nloc = (t >> 4) + 16 * i;
    int ch = t & 15;
    u16x8 v = *(const u16x8*)&lv[nloc * 144 + ch * 8];
    int nglob = n0 + nloc;
    int ktv = (klocal >> 5) + (ch >> 2);
    int s = (ch & 3) ^ (nglob & 3);
    *(u16x8*)(Vt + (((size_t)b * 128 + ktv) * NC + nglob) * 32 + s * 8) = v;
  }
}

// ---------- agg: out = dinv .* (Abf @ Vt) + bias (opt relu) ----------
// 2-phase dbuf, counted-drain, single raw barrier per K-tile (T3 minimum).
// BM=128, BK=32, BN = NC_ full width. 8 waves (2m x 4n), wave 64 x NC_/4.
template<int NC_, bool RELU>
__global__ __launch_bounds__(512, 2) void agg_kernel(const uint16_t* __restrict__ Abf,
                                                     const uint16_t* __restrict__ Vt,
                                                     const float* __restrict__ dinv,
                                                     const float* __restrict__ bias,
                                                     uint16_t* __restrict__ Hout,
                                                     float* __restrict__ Fout) {
  constexpr int FN  = NC_ / 64;               // n-frags per wave: 8 / 4
  constexpr int WNE = NC_ / 4;                // wave n extent: 128 / 64
  constexpr int VPW = NC_ / 128;              // V gl_lds instrs per wave: 4 / 2
  __shared__ uint16_t as_[2][4096];           // 2 x 8 KB
  __shared__ uint16_t vt_[2][NC_ * 32];       // 2 x 32/16 KB

  const int t = threadIdx.x;
  const int lane = t & 63, wid = t >> 6;
  const int wm = wid >> 2, wn = wid & 3;
  const int fr = lane & 15, c = lane >> 4;    // frag row sel, k-slot 0..3
  const int bid = blockIdx.x;
  const int b = bid & 7, mt = bid >> 3;       // XCD-pinned batch

  const uint16_t* Abase = Abf + ((size_t)(b * 32 + mt) << 19);
  const uint16_t* Vbase = Vt + (size_t)b * NC_ * 4096;

  auto stage = [&](int kt, int buf) {
    const uint16_t* At = Abase + (size_t)kt * 4096;
    const uint16_t* Vtile = Vbase + (size_t)kt * (NC_ * 32);
    gl_lds16(At + wid * 512 + lane * 8, &as_[buf][wid * 512]);
#pragma unroll
    for (int i = 0; i < VPW; ++i) {
      int cv = wid * VPW + i;
      gl_lds16(Vtile + cv * 512 + lane * 8, &vt_[buf][cv * 512]);
    }
  };

  f32x4 acc[4][FN] = {};

  stage(0, 0);
  asm volatile("s_waitcnt vmcnt(0)" ::: "memory");
  asm volatile("" ::: "memory");
  __builtin_amdgcn_s_barrier();
  __builtin_amdgcn_sched_barrier(0);

  for (int kt = 0; kt < 128; ++kt) {
    const int cur = kt & 1;
    if (kt < 127) stage(kt + 1, cur ^ 1);     // prefetch flies under MFMA
    bf16x8 afr[4], bfr[FN];
#pragma unroll
    for (int fm = 0; fm < 4; ++fm) {
      int row = wm * 64 + fm * 16 + fr;
      afr[fm] = *(const bf16x8*)&as_[cur][row * 32 + ((c ^ (row & 3)) << 3)];
    }
#pragma unroll
    for (int fn = 0; fn < FN; ++fn) {
      int n = wn * WNE + fn * 16 + fr;
      bfr[fn] = *(const bf16x8*)&vt_[cur][n * 32 + ((c ^ (n & 3)) << 3)];
    }
    __builtin_amdgcn_s_setprio(1);
#pragma unroll
    for (int fm = 0; fm < 4; ++fm)
#pragma unroll
      for (int fn = 0; fn < FN; ++fn)
        acc[fm][fn] = __builtin_amdgcn_mfma_f32_16x16x32_bf16(afr[fm], bfr[fn], acc[fm][fn], 0, 0, 0);
    __builtin_amdgcn_s_setprio(0);
    if (kt < 127) {
      asm volatile("s_waitcnt vmcnt(0)" ::: "memory");  // next tile landed
      asm volatile("" ::: "memory");
      __builtin_amdgcn_s_barrier();                     // publish to all waves
      __builtin_amdgcn_sched_barrier(0);
    }
  }
  // epilogue: row-side dinv + bias
#pragma unroll
  for (int fm = 0; fm < 4; ++fm)
#pragma unroll
    for (int r = 0; r < 4; ++r) {
      size_t grow = (size_t)b * NN + mt * 128 + wm * 64 + fm * 16 + (lane >> 4) * 4 + r;
      float dv = dinv[grow];
#pragma unroll
      for (int fn = 0; fn < FN; ++fn) {
        int col = wn * WNE + fn * 16 + fr;
        float v = acc[fm][fn][r] * dv + bias[col];
        if constexpr (RELU) {
          Hout[grow * NC_ + col] = f2b(fmaxf(v, 0.f));
        } else {
          Fout[grow * NC_ + col] = v;
        }
      }
    }
}

extern "C" void kernel_launch(void* const* d_in, const int* in_sizes, int n_in,
                              void* d_out, int out_size, void* d_ws, size_t ws_size,
                              hipStream_t stream) {
  const float* x  = (const float*)d_in[0];
  const float* A  = (const float*)d_in[1];
  const float* W1 = (const float*)d_in[2];
  const float* b1 = (const float*)d_in[3];
  const float* W2 = (const float*)d_in[4];
  const float* b2 = (const float*)d_in[5];
  float* out = (float*)d_out;

  char* ws = (char*)d_ws;
  uint16_t* Abf  = (uint16_t*)ws;                                    // 256 MB
  float*    dinv = (float*)(ws + 268435456);                         // 128 KB
  uint16_t* Vt   = (uint16_t*)(ws + 268435456 + 131072);             // 32 MB (V1 / V2)
  uint16_t* H    = (uint16_t*)(ws + 268435456 + 131072 + 33554432);  // 32 MB

  prep_kernel<<<256, 512, 0, stream>>>(A, Abf, dinv);
  xw_kernel<false, IC, HC><<<dim3(256, 4), 256, 0, stream>>>(x, W1, dinv, Vt);
  agg_kernel<HC, true><<<256, 512, 0, stream>>>(Abf, Vt, dinv, b1, H, nullptr);
  xw_kernel<true, HC, OC><<<dim3(256, 2), 256, 0, stream>>>(H, W2, dinv, Vt);
  agg_kernel<OC, false><<<256, 512, 0, stream>>>(Abf, Vt, dinv, b2, nullptr, out);
}

// Round 4
// 1167.012 us; speedup vs baseline: 1.0575x; 1.0575x over previous
//
#include <hip/hip_runtime.h>
#include <stdint.h>

#define NN    4096
#define BATCH 8
#define IC    256
#define HC    512
#define OC    256

typedef float    f32x4  __attribute__((ext_vector_type(4)));
typedef __bf16   bf16x8 __attribute__((ext_vector_type(8)));
typedef uint16_t u16x8  __attribute__((ext_vector_type(8)));
typedef uint16_t u16x4  __attribute__((ext_vector_type(4)));

__device__ __forceinline__ uint16_t f2b(float f) {
  union { float f; uint32_t u; } v; v.f = f;
  return (uint16_t)((v.u + 0x7FFFu + ((v.u >> 16) & 1u)) >> 16);
}

__device__ __forceinline__ void gl_lds16(const void* g, void* l) {
  __builtin_amdgcn_global_load_lds(
      (const __attribute__((address_space(1))) uint32_t*)g,
      (__attribute__((address_space(3))) uint32_t*)l, 16, 0, 0);
}

// ---------- pass1: rowsum->dinv  +  Abf = bf16(A + I), tiled+swizzled ----------
// Abf layout: [strip = b*32+mt][chunk 128][row 128][slot 4][8]; slot s holds
// k-group g = s ^ (row&3). Chunk (strip,kt) = 8 KB contiguous.
__global__ __launch_bounds__(512) void prep_kernel(const float* __restrict__ A,
                                                   uint16_t* __restrict__ Abf,
                                                   float* __restrict__ dinv) {
  const int bid = blockIdx.x;                 // 256 = 8 b * 32 strips
  const int b = bid & 7, mt = bid >> 3;
  const int t = threadIdx.x;
  const int r = t >> 2, g = t & 3;            // row 0..127, k-group 0..3
  const int rowl = mt * 128 + r;
  const float* Ap = A + ((size_t)b * NN + rowl) * NN + g * 8;
  uint16_t* Op = Abf + ((size_t)(b * 32 + mt) << 19) + r * 32 + ((g ^ (r & 3)) << 3);
  float s = 0.f;
  for (int kt = 0; kt < 128; ++kt) {
    f32x4 a0 = *(const f32x4*)(Ap + kt * 32);
    f32x4 a1 = *(const f32x4*)(Ap + kt * 32 + 4);
    int dj = rowl - (kt * 32 + g * 8);
    u16x8 o;
#pragma unroll
    for (int e = 0; e < 4; ++e) {
      float v0 = a0[e], v1 = a1[e];
      s += v0 + v1;
      if (dj == e)     v0 += 1.f;
      if (dj == e + 4) v1 += 1.f;
      o[e] = f2b(v0); o[e + 4] = f2b(v1);
    }
    *(u16x8*)(Op + (size_t)kt * 4096) = o;
  }
  __shared__ float red[512];
  red[t] = s;
  __syncthreads();
  if (t < 128) {
    float deg = red[t * 4] + red[t * 4 + 1] + red[t * 4 + 2] + red[t * 4 + 3] + 1.0f;
    dinv[b * NN + mt * 128 + t] = 1.0f / sqrtf(deg);
  }
}

// ---------- xw: Vt = (dinv .* (X @ W))^T, swizzled 32-k chunks ----------
// Vt layout: [b][chunk 128][n NC][slot 4][8], slot s holds k-group s^(n&3)
template<bool ABF16, int KTOT, int NC>
__global__ __launch_bounds__(256, 2) void xw_kernel(const void* __restrict__ Av,
                                                    const float* __restrict__ W,
                                                    const float* __restrict__ dinv,
                                                    uint16_t* __restrict__ Vt) {
  constexpr int LDT = 72;
  __shared__ uint16_t smem[18432];
  uint16_t* as_ = smem;
  uint16_t* wt_ = smem + 9216;
  const int t = threadIdx.x;
  const int m0 = blockIdx.x * 128;
  const int n0 = blockIdx.y * 128;
  const int lane = t & 63, wid = t >> 6;
  const int wm = wid >> 1, wn = wid & 1;
  f32x4 acc[4][4] = {};

  for (int kt = 0; kt < KTOT / 64; ++kt) {
    const int k0 = kt * 64;
    __syncthreads();
    if constexpr (!ABF16) {
      const float* Ap = (const float*)Av;
      const int c4 = t & 15, r0 = t >> 4;
#pragma unroll
      for (int i = 0; i < 8; ++i) {
        int r = r0 + 16 * i;
        f32x4 v = *(const f32x4*)(Ap + (size_t)(m0 + r) * KTOT + k0 + c4 * 4);
        uint32_t lo = f2b(v[0]) | ((uint32_t)f2b(v[1]) << 16);
        uint32_t hi = f2b(v[2]) | ((uint32_t)f2b(v[3]) << 16);
        *(uint2*)&as_[r * LDT + c4 * 4] = make_uint2(lo, hi);
      }
    } else {
      const uint16_t* Ap = (const uint16_t*)Av;
      const int c8 = t & 7, r0 = t >> 3;
#pragma unroll
      for (int i = 0; i < 4; ++i) {
        int r = r0 + 32 * i;
        u16x8 v = *(const u16x8*)(Ap + (size_t)(m0 + r) * KTOT + k0 + c8 * 8);
        *(u16x8*)&as_[r * LDT + c8 * 8] = v;
      }
    }
    {
      const int n4 = t & 31, kq = t >> 5;
#pragma unroll
      for (int i = 0; i < 8; ++i) {
        int k = kq + 8 * i;
        f32x4 v = *(const f32x4*)(W + (size_t)(k0 + k) * NC + n0 + n4 * 4);
        uint16_t hv[4] = { f2b(v[0]), f2b(v[1]), f2b(v[2]), f2b(v[3]) };
#pragma unroll
        for (int w = 0; w < 4; ++w) {
          int we = (w + n4) & 3;
          wt_[(n4 * 4 + we) * LDT + k] = hv[we];
        }
      }
    }
    __syncthreads();
#pragma unroll
    for (int kk = 0; kk < 2; ++kk) {
      bf16x8 bfr[4], afr[4];
#pragma unroll
      for (int fn = 0; fn < 4; ++fn)
        bfr[fn] = *(const bf16x8*)&wt_[(wn * 64 + fn * 16 + (lane & 15)) * LDT + kk * 32 + (lane >> 4) * 8];
#pragma unroll
      for (int fm = 0; fm < 4; ++fm)
        afr[fm] = *(const bf16x8*)&as_[(wm * 64 + fm * 16 + (lane & 15)) * LDT + kk * 32 + (lane >> 4) * 8];
#pragma unroll
      for (int fm = 0; fm < 4; ++fm)
#pragma unroll
        for (int fn = 0; fn < 4; ++fn)
          acc[fm][fn] = __builtin_amdgcn_mfma_f32_16x16x32_bf16(afr[fm], bfr[fn], acc[fm][fn], 0, 0, 0);
    }
  }
  // transpose epilogue via LDS bounce; scale by dinv[row]; write swizzled Vt
  const int b = m0 >> 12;
  const int klocal = m0 & 4095;
  __syncthreads();
  uint16_t* lv = smem;                        // [128 n][144]
#pragma unroll
  for (int fm = 0; fm < 4; ++fm)
#pragma unroll
    for (int fn = 0; fn < 4; ++fn) {
      int nloc = wn * 64 + fn * 16 + (lane & 15);
      int ml0  = wm * 64 + fm * 16 + (lane >> 4) * 4;
      u16x4 pk;
#pragma unroll
      for (int r = 0; r < 4; ++r)
        pk[r] = f2b(acc[fm][fn][r] * dinv[m0 + ml0 + r]);
      *(u16x4*)&lv[nloc * 144 + ml0] = pk;
    }
  __syncthreads();
#pragma unroll
  for (int i = 0; i < 8; ++i) {
    int nloc = (t >> 4) + 16 * i;
    int ch = t & 15;
    u16x8 v = *(const u16x8*)&lv[nloc * 144 + ch * 8];
    int nglob = n0 + nloc;
    int ktv = (klocal >> 5) + (ch >> 2);
    int s = (ch & 3) ^ (nglob & 3);
    *(u16x8*)(Vt + (((size_t)b * 128 + ktv) * NC + nglob) * 32 + s * 8) = v;
  }
}

// ---------- agg: out = dinv .* (Abf @ Vt) + bias (opt relu) ----------
// BM=64, 4 waves (wave = 64m x NC_/4 n), grid 512 -> 2 blocks/CU for
// barrier-stagger latency hiding. 2-buffer, 1-deep prefetch, raw barrier.
template<int NC_, int BK_, bool RELU>
__global__ __launch_bounds__(256, 2) void agg_kernel(const uint16_t* __restrict__ Abf,
                                                     const uint16_t* __restrict__ Vt,
                                                     const float* __restrict__ dinv,
                                                     const float* __restrict__ bias,
                                                     uint16_t* __restrict__ Hout,
                                                     float* __restrict__ Fout) {
  constexpr int KCH = BK_ / 32;               // k-chunks per tile: 1 or 2
  constexpr int FN  = NC_ / 64;               // n-frags per wave: 8 / 4
  constexpr int WNE = NC_ / 4;                // wave n extent: 128 / 64
  constexpr int VIW = NC_ / 64;               // V gl_lds per wave per chunk
  constexpr int NT  = 128 / KCH;              // tiles
  __shared__ uint16_t as_[2][KCH * 2048];     // 2 x 4/8 KB
  __shared__ uint16_t vt_[2][KCH * NC_ * 32]; // 2 x 32 KB

  const int t = threadIdx.x;
  const int lane = t & 63, wid = t >> 6;
  const int fr = lane & 15, c = lane >> 4;
  const int bid = blockIdx.x;                 // 512 = 8 b * 64 mtb
  const int b = bid & 7, mtb = bid >> 3;      // XCD-pinned batch

  const uint16_t* Abase = Abf + (((size_t)(b * 32 + (mtb >> 1))) << 19) + (mtb & 1) * 2048;
  const uint16_t* Vbase = Vt + (size_t)b * NC_ * 4096;

  auto stage = [&](int kt, int buf) {
#pragma unroll
    for (int ch = 0; ch < KCH; ++ch) {
      const uint16_t* At = Abase + (size_t)(kt * KCH + ch) * 4096;
      gl_lds16(At + wid * 512 + lane * 8, &as_[buf][ch * 2048 + wid * 512]);
      const uint16_t* Vtile = Vbase + (size_t)(kt * KCH + ch) * (NC_ * 32);
#pragma unroll
      for (int i = 0; i < VIW; ++i) {
        int cv = wid * VIW + i;
        gl_lds16(Vtile + cv * 512 + lane * 8, &vt_[buf][ch * NC_ * 32 + cv * 512]);
      }
    }
  };

  f32x4 acc[4][FN] = {};

  stage(0, 0);
  asm volatile("s_waitcnt vmcnt(0)" ::: "memory");
  __builtin_amdgcn_s_barrier();
  __builtin_amdgcn_sched_barrier(0);

  for (int kt = 0; kt < NT; ++kt) {
    const int cur = kt & 1;
    if (kt + 1 < NT) stage(kt + 1, cur ^ 1);  // prefetch flies under MFMA
#pragma unroll
    for (int kk = 0; kk < KCH; ++kk) {
      bf16x8 afr[4], bfr[FN];
#pragma unroll
      for (int fm = 0; fm < 4; ++fm) {
        int row = fm * 16 + fr;
        afr[fm] = *(const bf16x8*)&as_[cur][kk * 2048 + row * 32 + ((c ^ (fr & 3)) << 3)];
      }
#pragma unroll
      for (int fn = 0; fn < FN; ++fn) {
        int n = wid * WNE + fn * 16 + fr;
        bfr[fn] = *(const bf16x8*)&vt_[cur][kk * NC_ * 32 + n * 32 + ((c ^ (fr & 3)) << 3)];
      }
      __builtin_amdgcn_s_setprio(1);
#pragma unroll
      for (int fm = 0; fm < 4; ++fm)
#pragma unroll
        for (int fn = 0; fn < FN; ++fn)
          acc[fm][fn] = __builtin_amdgcn_mfma_f32_16x16x32_bf16(afr[fm], bfr[fn], acc[fm][fn], 0, 0, 0);
      __builtin_amdgcn_s_setprio(0);
    }
    if (kt + 1 < NT) {
      asm volatile("s_waitcnt vmcnt(0)" ::: "memory");  // next tile landed
      __builtin_amdgcn_s_barrier();                     // publish to all waves
      __builtin_amdgcn_sched_barrier(0);
    }
  }
  // epilogue: row-side dinv + bias
#pragma unroll
  for (int fm = 0; fm < 4; ++fm)
#pragma unroll
    for (int r = 0; r < 4; ++r) {
      size_t grow = (size_t)b * NN + mtb * 64 + fm * 16 + (lane >> 4) * 4 + r;
      float dv = dinv[grow];
#pragma unroll
      for (int fn = 0; fn < FN; ++fn) {
        int col = wid * WNE + fn * 16 + fr;
        float v = acc[fm][fn][r] * dv + bias[col];
        if constexpr (RELU) {
          Hout[grow * NC_ + col] = f2b(fmaxf(v, 0.f));
        } else {
          Fout[grow * NC_ + col] = v;
        }
      }
    }
}

extern "C" void kernel_launch(void* const* d_in, const int* in_sizes, int n_in,
                              void* d_out, int out_size, void* d_ws, size_t ws_size,
                              hipStream_t stream) {
  const float* x  = (const float*)d_in[0];
  const float* A  = (const float*)d_in[1];
  const float* W1 = (const float*)d_in[2];
  const float* b1 = (const float*)d_in[3];
  const float* W2 = (const float*)d_in[4];
  const float* b2 = (const float*)d_in[5];
  float* out = (float*)d_out;

  char* ws = (char*)d_ws;
  uint16_t* Abf  = (uint16_t*)ws;                                    // 256 MB
  float*    dinv = (float*)(ws + 268435456);                         // 128 KB
  uint16_t* Vt   = (uint16_t*)(ws + 268435456 + 131072);             // 32 MB (V1 / V2)
  uint16_t* H    = (uint16_t*)(ws + 268435456 + 131072 + 33554432);  // 32 MB

  prep_kernel<<<256, 512, 0, stream>>>(A, Abf, dinv);
  xw_kernel<false, IC, HC><<<dim3(256, 4), 256, 0, stream>>>(x, W1, dinv, Vt);
  agg_kernel<HC, 32, true><<<512, 256, 0, stream>>>(Abf, Vt, dinv, b1, H, nullptr);
  xw_kernel<true, HC, OC><<<dim3(256, 2), 256, 0, stream>>>(H, W2, dinv, Vt);
  agg_kernel<OC, 64, false><<<512, 256, 0, stream>>>(Abf, Vt, dinv, b2, nullptr, out);
}